// Round 8
// baseline (288.213 us; speedup 1.0000x reference)
//
#include <hip/hip_runtime.h>
#include <stdint.h>
#include <math.h>

#define HW   4096
#define NB   8
#define NC   512
#define C2   256
#define PT   32     // p-tile per block in argmax kernel
#define QC   256    // q-chunk per block (4 k per lane via one float4)

// ---------- ws layout (bytes) ----------
#define WS_PACKED 0         // u64 packed[8*4096]            = 262144
#define WS_INVN   262144    // f32 invn[8*4096]              = 131072
#define WS_Q0     393216    // i32 q0list[4096]              = 16384
#define WS_P1     409600    // i32 p1list[4096]              = 16384
#define WS_CNT    425984    // i32 cnt[2]
#define WS_IDX    427008    // i32 idx[8*4096]               = 131072
#define WS_INVC   558080    // f32 invc[8*4096]              = 131072

__device__ __forceinline__ unsigned long long mkkey(float v, unsigned q) {
    unsigned u = __float_as_uint(v);
    u = (u & 0x80000000u) ? ~u : (u | 0x80000000u);   // monotone float -> u32
    return ((unsigned long long)u << 32) | (unsigned long long)(0xFFFFFFFFu - q);
}

// Packed scratch lives in d_out's shift region (channels [512,768) of batch b)
// = 1M floats per batch. lfc (C2 x ns) + ffc (C2 x ms) = 256*(3072+1024) = 1M
// exactly (n0+n1 == 4096, both multiples of 4 for this flag). Written by
// pack kernels, read by argmax, then fully overwritten by shift_kernel.
__device__ __forceinline__ float* lfc_region(float* out, int b) {
    return out + ((size_t)b * 768 + 512) * HW;
}

// --- 1. deterministic sorted compaction of flag into p1 (flag==1) / q0 (flag==0)
__global__ void compact_kernel(const int* __restrict__ flag, int* __restrict__ q0,
                               int* __restrict__ p1, int* __restrict__ cnt) {
    __shared__ int c1s[256];
    int t = threadIdx.x;
    int f[16]; int n1 = 0;
    #pragma unroll
    for (int j = 0; j < 16; ++j) { f[j] = flag[t*16 + j]; n1 += (f[j] == 1); }
    c1s[t] = n1;
    __syncthreads();
    if (t == 0) {
        int run = 0;
        for (int i = 0; i < 256; ++i) { int v = c1s[i]; c1s[i] = run; run += v; }
        cnt[0] = run;          // n1
        cnt[1] = HW - run;     // n0
    }
    __syncthreads();
    int b1 = c1s[t];
    int b0 = t*16 - c1s[t];
    for (int j = 0; j < 16; ++j) {
        int i = t*16 + j;
        if (f[j] == 1) p1[b1++] = i; else q0[b0++] = i;
    }
}

// --- 2. inv norms of latter columns
__global__ void norm_kernel(const float* __restrict__ x, float* __restrict__ invn) {
    int b = blockIdx.y;
    int q = blockIdx.x * 256 + threadIdx.x;
    const float* lf = x + ((size_t)b * NC + C2) * HW + q;
    float s = 0.f;
    #pragma unroll 8
    for (int c = 0; c < C2; ++c) {
        float v = lf[c * HW];
        s = fmaf(v, v, s);
    }
    invn[b * HW + q] = 1.0f / fmaxf(sqrtf(s), 1e-8f);
}

// --- 2b. pack lf: lfc[b][c][k] = lf[b][c][q0[k]], invc[b][k] = invn[b][q0[k]]
__global__ void pack_lf_kernel(const float* __restrict__ x, const float* __restrict__ invn,
                               const int* __restrict__ q0, const int* __restrict__ cnt,
                               float* __restrict__ out, float* __restrict__ invc) {
    int b = blockIdx.z, c = blockIdx.y;
    int n0 = cnt[1];
    int ns = (n0 + 3) & ~3;
    int k = blockIdx.x * 256 + threadIdx.x;
    if (k >= n0) return;
    int q = q0[k];
    float* lfc = lfc_region(out, b);
    lfc[(size_t)c * ns + k] = x[((size_t)b * NC + C2 + c) * HW + q];
    if (c == 0) invc[b * HW + k] = invn[b * HW + q];
}

// --- 2c. pack ff: ffc[b][c][m] = ff[b][c][p1[m]]
__global__ void pack_ff_kernel(const float* __restrict__ x, const int* __restrict__ p1,
                               const int* __restrict__ cnt, float* __restrict__ out) {
    int b = blockIdx.z, c = blockIdx.y;
    int n1 = cnt[0], n0 = cnt[1];
    int ns = (n0 + 3) & ~3, ms = (n1 + 3) & ~3;
    int m = blockIdx.x * 256 + threadIdx.x;
    if (m >= n1) return;
    float* ffc = lfc_region(out, b) + (size_t)C2 * ns;
    ffc[(size_t)c * ms + m] = x[((size_t)b * NC + c) * HW + p1[m]];
}

// --- 3. cos + argmax over unmasked q, merged via packed atomicMax
//     grid: (HW/PT tiles, HW/QC chunks, NB); dead blocks exit.
//     Both operand streams packed+coalesced: ff tile staged to LDS in two
//     c-halves (16.5 KB) from ffc via float4; lf read per c as ONE coalesced
//     float4 per lane from lfc (L2-resident). acc[8][4] = 32 regs targets
//     VGPR <= 64 -> 8 waves/SIMD; 12 live blocks/CU hide latency via TLP.
//     NOTE: no min-waves clamp in launch_bounds — (256,4) forced VGPR=64
//     and spilled acc to scratch (13 GB HBM, 7x regression in R3).
__global__ void __launch_bounds__(256) argmax_kernel(
        float* __restrict__ out, const float* __restrict__ invc,
        const int* __restrict__ q0, const int* __restrict__ p1,
        const int* __restrict__ cnt, unsigned long long* __restrict__ packed) {
    int tile  = blockIdx.x;
    int chunk = blockIdx.y;
    int b     = blockIdx.z;
    int n1 = cnt[0], n0 = cnt[1];
    if (tile * PT >= n1) return;
    if (chunk * QC >= n0) return;
    int ns = (n0 + 3) & ~3, ms = (n1 + 3) & ~3;

    __shared__ float sff[128][PT];   // ff half-tile: [c][p] 16 KB

    int t = threadIdx.x;
    int tp = t >> 6;   // wave id -> 8-p sub-tile
    int tq = t & 63;   // lane    -> k group

    const float* lfc = lfc_region(out, b);
    const float* ffc = lfc + (size_t)C2 * ns;
    int kbase = chunk * QC + tq * 4;   // 16B aligned

    const float* r = lfc + kbase;      // marches by ns per c
    float4 bv = *(const float4*)r;     // c = 0

    float acc[8][4];
    #pragma unroll
    for (int pi = 0; pi < 8; ++pi)
        #pragma unroll
        for (int j = 0; j < 4; ++j) acc[pi][j] = 0.f;

    bool fulltile = (tile * PT + PT <= n1);

    for (int h = 0; h < 2; ++h) {
        __syncthreads();   // h=1: all waves done reading sff half 0
        if (fulltile) {
            #pragma unroll
            for (int k = 0; k < 4; ++k) {       // 1024 float4 / 256 threads
                int i4 = t + (k << 8);
                int c = i4 >> 3, jg = i4 & 7;
                ((float4*)sff)[i4] =
                    *(const float4*)&ffc[(size_t)(h * 128 + c) * ms + tile * PT + jg * 4];
            }
        } else {
            #pragma unroll
            for (int k = 0; k < 4; ++k) {
                int i4 = t + (k << 8);
                int c = i4 >> 3, jg = i4 & 7;
                const float* src = &ffc[(size_t)(h * 128 + c) * ms];
                int m0 = tile * PT + jg * 4;
                float4 v;
                v.x = (m0 + 0 < n1) ? src[m0 + 0] : 0.f;
                v.y = (m0 + 1 < n1) ? src[m0 + 1] : 0.f;
                v.z = (m0 + 2 < n1) ? src[m0 + 2] : 0.f;
                v.w = (m0 + 3 < n1) ? src[m0 + 3] : 0.f;
                ((float4*)sff)[i4] = v;
            }
        }
        __syncthreads();

        #pragma unroll 2
        for (int cc = 0; cc < 128; ++cc) {
            int cglob = h * 128 + cc;
            const float* prow = (cglob < 255) ? (r + ns) : r;   // clamp at last row
            float4 nb = *(const float4*)prow;                   // prefetch c+1
            const float4* arow = (const float4*)&sff[cc][tp * 8];
            float4 a0 = arow[0], a1 = arow[1];
            float av[8] = {a0.x, a0.y, a0.z, a0.w, a1.x, a1.y, a1.z, a1.w};
            #pragma unroll
            for (int pi = 0; pi < 8; ++pi) {
                acc[pi][0] = fmaf(av[pi], bv.x, acc[pi][0]);
                acc[pi][1] = fmaf(av[pi], bv.y, acc[pi][1]);
                acc[pi][2] = fmaf(av[pi], bv.z, acc[pi][2]);
                acc[pi][3] = fmaf(av[pi], bv.w, acc[pi][3]);
            }
            bv = nb;
            r = prow;
        }
    }

    float best[8];
    int   bq[8];
    #pragma unroll
    for (int pi = 0; pi < 8; ++pi) { best[pi] = -INFINITY; bq[pi] = 0x7FFFFFFF; }

    #pragma unroll
    for (int j = 0; j < 4; ++j) {
        int k = kbase + j;
        if (k >= n0) continue;
        float sc = invc[b * HW + k];
        int   q  = q0[k];
        #pragma unroll
        for (int pi = 0; pi < 8; ++pi) {
            float cv = acc[pi][j] * sc;
            if (cv > best[pi] || (cv == best[pi] && q < bq[pi])) {
                best[pi] = cv; bq[pi] = q;
            }
        }
    }

    // wave reduce (all 64 lanes share the same 8 p's)
    #pragma unroll
    for (int m = 1; m < 64; m <<= 1) {
        #pragma unroll
        for (int pi = 0; pi < 8; ++pi) {
            float ov = __shfl_xor(best[pi], m);
            int   oq = __shfl_xor(bq[pi], m);
            if (ov > best[pi] || (ov == best[pi] && oq < bq[pi])) {
                best[pi] = ov; bq[pi] = oq;
            }
        }
    }
    if (tq == 0) {
        #pragma unroll
        for (int pi = 0; pi < 8; ++pi) {
            int pidx = tile * PT + tp * 8 + pi;
            int p = (pidx < n1) ? p1[pidx] : -1;
            if (p >= 0)
                atomicMax(&packed[(size_t)b * HW + p], mkkey(best[pi], (unsigned)bq[pi]));
        }
    }
}

// --- 4. decode packed keys -> idx
__global__ void decode_kernel(const unsigned long long* __restrict__ packed,
                              const int* __restrict__ flag, int* __restrict__ idx) {
    int b = blockIdx.y, p = blockIdx.x * 256 + threadIdx.x;
    int q = 0;
    if (flag[p] == 1) {
        unsigned low = (unsigned)(packed[(size_t)b * HW + p] & 0xFFFFFFFFull);
        q = (int)((0xFFFFFFFFu - low) & (HW - 1));
    }
    idx[b * HW + p] = q;
}

// --- 5. copy former+latter -> out channels [0,512)
__global__ void copy_kernel(const float4* __restrict__ x4, float4* __restrict__ out4) {
    size_t i = (size_t)blockIdx.x * 256 + threadIdx.x;
    if (i >= (size_t)NB * NC * (HW / 4)) return;
    size_t p4 = i & 1023;
    size_t c  = (i >> 10) & 511;
    size_t b  = i >> 19;
    out4[(b * 768 + c) * 1024 + p4] = x4[i];
}

// --- 6. shift writeback: out[b, 512+c, p] = flag[p] ? lf[b, c, idx[b,p]] : 0
//     (fully overwrites the lfc/ffc scratch region — must run after argmax)
__global__ void shift_kernel(const float* __restrict__ x, const int* __restrict__ flag,
                             const int* __restrict__ idx, float* __restrict__ out) {
    int cc = blockIdx.x, b = blockIdx.y;
    const float* lfrow = x + ((size_t)b * NC + C2 + cc) * HW;
    float*       orow  = out + ((size_t)b * 768 + 512 + cc) * HW;
    const int*   idxb  = idx + b * HW;
    for (int p = threadIdx.x; p < HW; p += 256) {
        float v = 0.f;
        if (flag[p] == 1) v = lfrow[idxb[p]];
        orow[p] = v;
    }
}

extern "C" void kernel_launch(void* const* d_in, const int* in_sizes, int n_in,
                              void* d_out, int out_size, void* d_ws, size_t ws_size,
                              hipStream_t stream) {
    const float* x    = (const float*)d_in[0];
    const int*   flag = (const int*)d_in[1];
    float*       out  = (float*)d_out;
    char*        ws   = (char*)d_ws;

    unsigned long long* packed = (unsigned long long*)(ws + WS_PACKED);
    float* invn = (float*)(ws + WS_INVN);
    int*   q0   = (int*)(ws + WS_Q0);
    int*   p1   = (int*)(ws + WS_P1);
    int*   cnt  = (int*)(ws + WS_CNT);
    int*   idx  = (int*)(ws + WS_IDX);
    float* invc = (float*)(ws + WS_INVC);

    hipMemsetAsync(packed, 0, (size_t)NB * HW * sizeof(unsigned long long), stream);

    compact_kernel<<<1, 256, 0, stream>>>(flag, q0, p1, cnt);
    norm_kernel<<<dim3(HW / 256, NB), 256, 0, stream>>>(x, invn);
    pack_lf_kernel<<<dim3(HW / 256, C2, NB), 256, 0, stream>>>(x, invn, q0, cnt, out, invc);
    pack_ff_kernel<<<dim3(HW / 256, C2, NB), 256, 0, stream>>>(x, p1, cnt, out);
    copy_kernel<<<(NB * NC * (HW / 4) + 255) / 256, 256, 0, stream>>>((const float4*)x, (float4*)out);
    argmax_kernel<<<dim3(HW / PT, HW / QC, NB), 256, 0, stream>>>(out, invc, q0, p1, cnt, packed);
    decode_kernel<<<dim3(HW / 256, NB), 256, 0, stream>>>(packed, flag, idx);
    shift_kernel<<<dim3(C2, NB), 256, 0, stream>>>(x, flag, idx, out);
}

// Round 9
// 281.073 us; speedup vs baseline: 1.0254x; 1.0254x over previous
//
#include <hip/hip_runtime.h>
#include <stdint.h>
#include <math.h>

#define HW   4096
#define NB   8
#define NC   512
#define C2   256
#define PT   32     // p-tile per block in argmax kernel
#define QC   256    // q-chunk per block (4 k per lane via one float4)
#define NCHUNK (HW / QC)   // 16 (chunks >= n0/QC exit)

// ---------- ws layout (bytes) ----------
#define WS_PACKED 0         // u64 packed[8*4096]            = 262144
#define WS_INVN   262144    // f32 invn[8*4096]              = 131072
#define WS_Q0     393216    // i32 q0list[4096]              = 16384
#define WS_P1     409600    // i32 p1list[4096]              = 16384
#define WS_CNT    425984    // i32 cnt[2]
#define WS_INVC   558080    // f32 invc[8*4096]              = 131072

__device__ __forceinline__ unsigned long long mkkey(float v, unsigned q) {
    unsigned u = __float_as_uint(v);
    u = (u & 0x80000000u) ? ~u : (u | 0x80000000u);   // monotone float -> u32
    return ((unsigned long long)u << 32) | (unsigned long long)(0xFFFFFFFFu - q);
}

// Packed scratch lives in d_out's shift region (channels [512,768) of batch b)
// = 1M floats per batch. lfc (C2 x ns) + ffc (C2 x ms) = 256*(3072+1024) = 1M
// exactly. Written by pack_kernel, read by argmax, then fully overwritten by
// shift_kernel.
__device__ __forceinline__ float* lfc_region(float* out, int b) {
    return out + ((size_t)b * 768 + 512) * HW;
}

// --- 1. deterministic sorted compaction of flag into p1 (flag==1) / q0 (flag==0)
__global__ void compact_kernel(const int* __restrict__ flag, int* __restrict__ q0,
                               int* __restrict__ p1, int* __restrict__ cnt) {
    __shared__ int c1s[256];
    int t = threadIdx.x;
    int f[16]; int n1 = 0;
    #pragma unroll
    for (int j = 0; j < 16; ++j) { f[j] = flag[t*16 + j]; n1 += (f[j] == 1); }
    c1s[t] = n1;
    __syncthreads();
    if (t == 0) {
        int run = 0;
        for (int i = 0; i < 256; ++i) { int v = c1s[i]; c1s[i] = run; run += v; }
        cnt[0] = run;          // n1
        cnt[1] = HW - run;     // n0
    }
    __syncthreads();
    int b1 = c1s[t];
    int b0 = t*16 - c1s[t];
    for (int j = 0; j < 16; ++j) {
        int i = t*16 + j;
        if (f[j] == 1) p1[b1++] = i; else q0[b0++] = i;
    }
}

// --- 2. inv norms of latter columns
__global__ void norm_kernel(const float* __restrict__ x, float* __restrict__ invn) {
    int b = blockIdx.y;
    int q = blockIdx.x * 256 + threadIdx.x;
    const float* lf = x + ((size_t)b * NC + C2) * HW + q;
    float s = 0.f;
    #pragma unroll 8
    for (int c = 0; c < C2; ++c) {
        float v = lf[c * HW];
        s = fmaf(v, v, s);
    }
    invn[b * HW + q] = 1.0f / fmaxf(sqrtf(s), 1e-8f);
}

// --- 2b. fused pack: cy<256 -> lfc[b][cy][k] = lf[b][cy][q0[k]] (+invc at cy=0)
//                     cy>=256 -> ffc[b][cy-256][m] = ff[b][cy-256][p1[m]]
__global__ void pack_kernel(const float* __restrict__ x, const float* __restrict__ invn,
                            const int* __restrict__ q0, const int* __restrict__ p1,
                            const int* __restrict__ cnt,
                            float* __restrict__ out, float* __restrict__ invc) {
    int b = blockIdx.z, cy = blockIdx.y;
    int n1 = cnt[0], n0 = cnt[1];
    int ns = (n0 + 3) & ~3, ms = (n1 + 3) & ~3;
    int i = blockIdx.x * 256 + threadIdx.x;
    if (cy < C2) {
        if (i >= n0) return;
        int q = q0[i];
        float* lfc = lfc_region(out, b);
        lfc[(size_t)cy * ns + i] = x[((size_t)b * NC + C2 + cy) * HW + q];
        if (cy == 0) invc[b * HW + i] = invn[b * HW + q];
    } else {
        int c = cy - C2;
        if (i >= n1) return;
        float* ffc = lfc_region(out, b) + (size_t)C2 * ns;
        ffc[(size_t)c * ms + i] = x[((size_t)b * NC + c) * HW + p1[i]];
    }
}

// --- 3. cos + argmax over unmasked q, merged via packed atomicMax
//     1D grid, XCD-swizzled: bid = b + 8*(chunk*32 + tile) so ALL of batch
//     b's blocks land on XCD b (round-robin mod 8); working set per XCD =
//     lfc 3MB + ffc 1MB = 4MB = one XCD L2 -> lf stream is L2-resident
//     (R8: FETCH 148MB = 4x re-fetch from cross-XCD thrash).
//     Inner loop (R8, unchanged): per c, 1 coalesced float4 from lfc +
//     2 ds_read_b128 + 32 FMA; acc[8][4] keeps VGPR=36 -> 60% occupancy.
//     NOTE: no min-waves clamp in launch_bounds — (256,4) forced VGPR=64
//     and spilled acc to scratch (13 GB HBM, 7x regression in R3).
__global__ void __launch_bounds__(256) argmax_kernel(
        float* __restrict__ out, const float* __restrict__ invc,
        const int* __restrict__ q0, const int* __restrict__ p1,
        const int* __restrict__ cnt, unsigned long long* __restrict__ packed) {
    int bid   = blockIdx.x;
    int b     = bid & 7;
    int s     = bid >> 3;
    int chunk = s >> 5;
    int tile  = s & 31;
    int n1 = cnt[0], n0 = cnt[1];
    if (tile * PT >= n1) return;
    if (chunk * QC >= n0) return;
    int ns = (n0 + 3) & ~3, ms = (n1 + 3) & ~3;

    __shared__ float sff[128][PT];   // ff half-tile: [c][p] 16 KB

    int t = threadIdx.x;
    int tp = t >> 6;   // wave id -> 8-p sub-tile
    int tq = t & 63;   // lane    -> k group

    const float* lfc = lfc_region(out, b);
    const float* ffc = lfc + (size_t)C2 * ns;
    int kbase = chunk * QC + tq * 4;   // 16B aligned

    const float* r = lfc + kbase;      // marches by ns per c
    float4 bv = *(const float4*)r;     // c = 0

    float acc[8][4];
    #pragma unroll
    for (int pi = 0; pi < 8; ++pi)
        #pragma unroll
        for (int j = 0; j < 4; ++j) acc[pi][j] = 0.f;

    bool fulltile = (tile * PT + PT <= n1);

    for (int h = 0; h < 2; ++h) {
        __syncthreads();   // h=1: all waves done reading sff half 0
        if (fulltile) {
            #pragma unroll
            for (int k = 0; k < 4; ++k) {       // 1024 float4 / 256 threads
                int i4 = t + (k << 8);
                int c = i4 >> 3, jg = i4 & 7;
                ((float4*)sff)[i4] =
                    *(const float4*)&ffc[(size_t)(h * 128 + c) * ms + tile * PT + jg * 4];
            }
        } else {
            #pragma unroll
            for (int k = 0; k < 4; ++k) {
                int i4 = t + (k << 8);
                int c = i4 >> 3, jg = i4 & 7;
                const float* src = &ffc[(size_t)(h * 128 + c) * ms];
                int m0 = tile * PT + jg * 4;
                float4 v;
                v.x = (m0 + 0 < n1) ? src[m0 + 0] : 0.f;
                v.y = (m0 + 1 < n1) ? src[m0 + 1] : 0.f;
                v.z = (m0 + 2 < n1) ? src[m0 + 2] : 0.f;
                v.w = (m0 + 3 < n1) ? src[m0 + 3] : 0.f;
                ((float4*)sff)[i4] = v;
            }
        }
        __syncthreads();

        #pragma unroll 2
        for (int cc = 0; cc < 128; ++cc) {
            int cglob = h * 128 + cc;
            const float* prow = (cglob < 255) ? (r + ns) : r;   // clamp at last row
            float4 nb = *(const float4*)prow;                   // prefetch c+1
            const float4* arow = (const float4*)&sff[cc][tp * 8];
            float4 a0 = arow[0], a1 = arow[1];
            float av[8] = {a0.x, a0.y, a0.z, a0.w, a1.x, a1.y, a1.z, a1.w};
            #pragma unroll
            for (int pi = 0; pi < 8; ++pi) {
                acc[pi][0] = fmaf(av[pi], bv.x, acc[pi][0]);
                acc[pi][1] = fmaf(av[pi], bv.y, acc[pi][1]);
                acc[pi][2] = fmaf(av[pi], bv.z, acc[pi][2]);
                acc[pi][3] = fmaf(av[pi], bv.w, acc[pi][3]);
            }
            bv = nb;
            r = prow;
        }
    }

    float best[8];
    int   bq[8];
    #pragma unroll
    for (int pi = 0; pi < 8; ++pi) { best[pi] = -INFINITY; bq[pi] = 0x7FFFFFFF; }

    #pragma unroll
    for (int j = 0; j < 4; ++j) {
        int k = kbase + j;
        if (k >= n0) continue;
        float sc = invc[b * HW + k];
        int   q  = q0[k];
        #pragma unroll
        for (int pi = 0; pi < 8; ++pi) {
            float cv = acc[pi][j] * sc;
            if (cv > best[pi] || (cv == best[pi] && q < bq[pi])) {
                best[pi] = cv; bq[pi] = q;
            }
        }
    }

    // wave reduce (all 64 lanes share the same 8 p's)
    #pragma unroll
    for (int m = 1; m < 64; m <<= 1) {
        #pragma unroll
        for (int pi = 0; pi < 8; ++pi) {
            float ov = __shfl_xor(best[pi], m);
            int   oq = __shfl_xor(bq[pi], m);
            if (ov > best[pi] || (ov == best[pi] && oq < bq[pi])) {
                best[pi] = ov; bq[pi] = oq;
            }
        }
    }
    if (tq == 0) {
        #pragma unroll
        for (int pi = 0; pi < 8; ++pi) {
            int pidx = tile * PT + tp * 8 + pi;
            int p = (pidx < n1) ? p1[pidx] : -1;
            if (p >= 0)
                atomicMax(&packed[(size_t)b * HW + p], mkkey(best[pi], (unsigned)bq[pi]));
        }
    }
}

// --- 5. copy former+latter -> out channels [0,512)
__global__ void copy_kernel(const float4* __restrict__ x4, float4* __restrict__ out4) {
    size_t i = (size_t)blockIdx.x * 256 + threadIdx.x;
    if (i >= (size_t)NB * NC * (HW / 4)) return;
    size_t p4 = i & 1023;
    size_t c  = (i >> 10) & 511;
    size_t b  = i >> 19;
    out4[(b * 768 + c) * 1024 + p4] = x4[i];
}

// --- 6. shift writeback with inline decode:
//     out[b, 512+c, p] = flag[p] ? lf[b, c, argmax_q(packed)] : 0
//     (fully overwrites the lfc/ffc scratch region — must run after argmax)
__global__ void shift_kernel(const float* __restrict__ x, const int* __restrict__ flag,
                             const unsigned long long* __restrict__ packed,
                             float* __restrict__ out) {
    int cc = blockIdx.x, b = blockIdx.y;
    const float* lfrow = x + ((size_t)b * NC + C2 + cc) * HW;
    float*       orow  = out + ((size_t)b * 768 + 512 + cc) * HW;
    const unsigned long long* pk = packed + (size_t)b * HW;
    for (int p = threadIdx.x; p < HW; p += 256) {
        float v = 0.f;
        if (flag[p] == 1) {
            unsigned low = (unsigned)(pk[p] & 0xFFFFFFFFull);
            int q = (int)((0xFFFFFFFFu - low) & (HW - 1));
            v = lfrow[q];
        }
        orow[p] = v;
    }
}

extern "C" void kernel_launch(void* const* d_in, const int* in_sizes, int n_in,
                              void* d_out, int out_size, void* d_ws, size_t ws_size,
                              hipStream_t stream) {
    const float* x    = (const float*)d_in[0];
    const int*   flag = (const int*)d_in[1];
    float*       out  = (float*)d_out;
    char*        ws   = (char*)d_ws;

    unsigned long long* packed = (unsigned long long*)(ws + WS_PACKED);
    float* invn = (float*)(ws + WS_INVN);
    int*   q0   = (int*)(ws + WS_Q0);
    int*   p1   = (int*)(ws + WS_P1);
    int*   cnt  = (int*)(ws + WS_CNT);
    float* invc = (float*)(ws + WS_INVC);

    hipMemsetAsync(packed, 0, (size_t)NB * HW * sizeof(unsigned long long), stream);

    compact_kernel<<<1, 256, 0, stream>>>(flag, q0, p1, cnt);
    norm_kernel<<<dim3(HW / 256, NB), 256, 0, stream>>>(x, invn);
    pack_kernel<<<dim3(HW / 256, NC, NB), 256, 0, stream>>>(x, invn, q0, p1, cnt, out, invc);
    copy_kernel<<<(NB * NC * (HW / 4) + 255) / 256, 256, 0, stream>>>((const float4*)x, (float4*)out);
    argmax_kernel<<<dim3(NB * NCHUNK * 32), 256, 0, stream>>>(out, invc, q0, p1, cnt, packed);
    shift_kernel<<<dim3(C2, NB), 256, 0, stream>>>(x, flag, packed, out);
}

// Round 10
// 274.120 us; speedup vs baseline: 1.0514x; 1.0254x over previous
//
#include <hip/hip_runtime.h>
#include <stdint.h>
#include <math.h>

#define HW   4096
#define NB   8
#define NC   512
#define C2   256
#define PT   32     // p-tile per block in argmax kernel
#define QC   384    // q-chunk per block (6 k per lane via three float2)
#define NCHK 11     // ceil(HW/QC); dead chunks exit

// ---------- ws layout (bytes) ----------
#define WS_PACKED 0         // u64 packed[8*4096]            = 262144
#define WS_Q0     393216    // i32 q0list[4096]              = 16384
#define WS_P1     409600    // i32 p1list[4096]              = 16384
#define WS_CNT    425984    // i32 cnt[2]
#define WS_INVC   558080    // f32 invc[8*4096]              = 131072

__device__ __forceinline__ unsigned long long mkkey(float v, unsigned q) {
    unsigned u = __float_as_uint(v);
    u = (u & 0x80000000u) ? ~u : (u | 0x80000000u);   // monotone float -> u32
    return ((unsigned long long)u << 32) | (unsigned long long)(0xFFFFFFFFu - q);
}

// Packed scratch lives in d_out's shift region (channels [512,768) of batch b)
// = 1M floats per batch: lfc (C2 x ns) then ffc (C2 x ms). Written by
// pack_kernel, read by invc/argmax, then fully overwritten by shift_kernel.
__device__ __forceinline__ float* lfc_region(float* out, int b) {
    return out + ((size_t)b * 768 + 512) * HW;
}

// --- 1. deterministic sorted compaction of flag into p1 (flag==1) / q0 (flag==0)
__global__ void compact_kernel(const int* __restrict__ flag, int* __restrict__ q0,
                               int* __restrict__ p1, int* __restrict__ cnt) {
    __shared__ int c1s[256];
    int t = threadIdx.x;
    int f[16]; int n1 = 0;
    #pragma unroll
    for (int j = 0; j < 16; ++j) { f[j] = flag[t*16 + j]; n1 += (f[j] == 1); }
    c1s[t] = n1;
    __syncthreads();
    if (t == 0) {
        int run = 0;
        for (int i = 0; i < 256; ++i) { int v = c1s[i]; c1s[i] = run; run += v; }
        cnt[0] = run;          // n1
        cnt[1] = HW - run;     // n0
    }
    __syncthreads();
    int b1 = c1s[t];
    int b0 = t*16 - c1s[t];
    for (int j = 0; j < 16; ++j) {
        int i = t*16 + j;
        if (f[j] == 1) p1[b1++] = i; else q0[b0++] = i;
    }
}

// --- 2. fused pack: cy<256 -> lfc[b][cy][k] = lf[b][cy][q0[k]]
//                    cy>=256 -> ffc[b][cy-256][m] = ff[b][cy-256][p1[m]]
__global__ void pack_kernel(const float* __restrict__ x,
                            const int* __restrict__ q0, const int* __restrict__ p1,
                            const int* __restrict__ cnt, float* __restrict__ out) {
    int b = blockIdx.z, cy = blockIdx.y;
    int n1 = cnt[0], n0 = cnt[1];
    int ns = (n0 + 3) & ~3, ms = (n1 + 3) & ~3;
    int i = blockIdx.x * 256 + threadIdx.x;
    if (cy < C2) {
        if (i >= n0) return;
        float* lfc = lfc_region(out, b);
        lfc[(size_t)cy * ns + i] = x[((size_t)b * NC + C2 + cy) * HW + q0[i]];
    } else {
        int c = cy - C2;
        if (i >= n1) return;
        float* ffc = lfc_region(out, b) + (size_t)C2 * ns;
        ffc[(size_t)c * ms + i] = x[((size_t)b * NC + c) * HW + p1[i]];
    }
}

// --- 2b. invc from packed lfc (coalesced; same c-ascending fp32 sum order
//     as the original norm kernel -> bit-identical values at q0 columns)
__global__ void invc_kernel(const float* __restrict__ out, const int* __restrict__ cnt,
                            float* __restrict__ invc) {
    int b = blockIdx.y;
    int n0 = cnt[1];
    int ns = (n0 + 3) & ~3;
    int k = blockIdx.x * 256 + threadIdx.x;
    if (k >= n0) return;
    const float* lfc = lfc_region((float*)out, b) + k;
    float s = 0.f;
    #pragma unroll 8
    for (int c = 0; c < C2; ++c) {
        float v = lfc[(size_t)c * ns];
        s = fmaf(v, v, s);
    }
    invc[b * HW + k] = 1.0f / fmaxf(sqrtf(s), 1e-8f);
}

// --- 3. cos + argmax over unmasked q, merged via packed atomicMax
//     1D grid, XCD-swizzled: bid = b + 8*s -> all of batch b's blocks on
//     XCD b; lfc+ffc = 4MB = one XCD L2 (R9: FETCH 148->16.6 MB).
//     QC=384 so live blocks = 32 tiles x 8 chunks x 8 b = 2048 = exactly
//     8/CU = full residency in ONE round (R9's 12/CU ran rounds of 8+4,
//     second round at half occupancy = the 27% VALU idle).
//     acc[8][6] = 48 regs; target VGPR < 64 (waves/SIMD halves at 64).
//     NOTE: no min-waves clamp in launch_bounds — (256,4) forced VGPR=64
//     and spilled acc to scratch (13 GB HBM, 7x regression in R3).
__global__ void __launch_bounds__(256) argmax_kernel(
        float* __restrict__ out, const float* __restrict__ invc,
        const int* __restrict__ q0, const int* __restrict__ p1,
        const int* __restrict__ cnt, unsigned long long* __restrict__ packed) {
    int bid   = blockIdx.x;
    int b     = bid & 7;
    int s     = bid >> 3;
    int chunk = s >> 5;
    int tile  = s & 31;
    int n1 = cnt[0], n0 = cnt[1];
    if (tile * PT >= n1) return;
    if (chunk * QC >= n0) return;
    int ns = (n0 + 3) & ~3, ms = (n1 + 3) & ~3;

    __shared__ float sff[128][PT];   // ff half-tile: [c][p] 16 KB

    int t = threadIdx.x;
    int tp = t >> 6;   // wave id -> 8-p sub-tile
    int tq = t & 63;   // lane    -> k group of 6

    const float* lfc = lfc_region(out, b);
    const float* ffc = lfc + (size_t)C2 * ns;
    int kbase = chunk * QC + tq * 6;   // 8B aligned

    const float* r = lfc + kbase;      // marches by ns per c
    float2 b0 = *(const float2*)(r);
    float2 b1 = *(const float2*)(r + 2);
    float2 b2 = *(const float2*)(r + 4);

    float acc[8][6];
    #pragma unroll
    for (int pi = 0; pi < 8; ++pi)
        #pragma unroll
        for (int j = 0; j < 6; ++j) acc[pi][j] = 0.f;

    bool fulltile = (tile * PT + PT <= n1);

    for (int h = 0; h < 2; ++h) {
        __syncthreads();   // h=1: all waves done reading sff half 0
        if (fulltile) {
            #pragma unroll
            for (int k = 0; k < 4; ++k) {       // 1024 float4 / 256 threads
                int i4 = t + (k << 8);
                int c = i4 >> 3, jg = i4 & 7;
                ((float4*)sff)[i4] =
                    *(const float4*)&ffc[(size_t)(h * 128 + c) * ms + tile * PT + jg * 4];
            }
        } else {
            #pragma unroll
            for (int k = 0; k < 4; ++k) {
                int i4 = t + (k << 8);
                int c = i4 >> 3, jg = i4 & 7;
                const float* src = &ffc[(size_t)(h * 128 + c) * ms];
                int m0 = tile * PT + jg * 4;
                float4 v;
                v.x = (m0 + 0 < n1) ? src[m0 + 0] : 0.f;
                v.y = (m0 + 1 < n1) ? src[m0 + 1] : 0.f;
                v.z = (m0 + 2 < n1) ? src[m0 + 2] : 0.f;
                v.w = (m0 + 3 < n1) ? src[m0 + 3] : 0.f;
                ((float4*)sff)[i4] = v;
            }
        }
        __syncthreads();

        #pragma unroll 2
        for (int cc = 0; cc < 128; ++cc) {
            // unconditional prefetch of row c+1: one-past-last-row lands in
            // the ffc scratch (valid memory, value never used in a result)
            const float* prow = r + ns;
            float2 n0v = *(const float2*)(prow);
            float2 n1v = *(const float2*)(prow + 2);
            float2 n2v = *(const float2*)(prow + 4);
            const float4* arow = (const float4*)&sff[cc][tp * 8];
            float4 a0 = arow[0], a1 = arow[1];
            float av[8] = {a0.x, a0.y, a0.z, a0.w, a1.x, a1.y, a1.z, a1.w};
            float bvv[6] = {b0.x, b0.y, b1.x, b1.y, b2.x, b2.y};
            #pragma unroll
            for (int pi = 0; pi < 8; ++pi)
                #pragma unroll
                for (int j = 0; j < 6; ++j)
                    acc[pi][j] = fmaf(av[pi], bvv[j], acc[pi][j]);
            b0 = n0v; b1 = n1v; b2 = n2v;
            r = prow;
        }
    }

    float best[8];
    int   bq[8];
    #pragma unroll
    for (int pi = 0; pi < 8; ++pi) { best[pi] = -INFINITY; bq[pi] = 0x7FFFFFFF; }

    #pragma unroll
    for (int j = 0; j < 6; ++j) {
        int k = kbase + j;
        if (k >= n0) continue;
        float sc = invc[b * HW + k];
        int   q  = q0[k];
        #pragma unroll
        for (int pi = 0; pi < 8; ++pi) {
            float cv = acc[pi][j] * sc;
            if (cv > best[pi] || (cv == best[pi] && q < bq[pi])) {
                best[pi] = cv; bq[pi] = q;
            }
        }
    }

    // wave reduce (all 64 lanes share the same 8 p's)
    #pragma unroll
    for (int m = 1; m < 64; m <<= 1) {
        #pragma unroll
        for (int pi = 0; pi < 8; ++pi) {
            float ov = __shfl_xor(best[pi], m);
            int   oq = __shfl_xor(bq[pi], m);
            if (ov > best[pi] || (ov == best[pi] && oq < bq[pi])) {
                best[pi] = ov; bq[pi] = oq;
            }
        }
    }
    if (tq == 0) {
        #pragma unroll
        for (int pi = 0; pi < 8; ++pi) {
            int pidx = tile * PT + tp * 8 + pi;
            int p = (pidx < n1) ? p1[pidx] : -1;
            if (p >= 0)
                atomicMax(&packed[(size_t)b * HW + p], mkkey(best[pi], (unsigned)bq[pi]));
        }
    }
}

// --- 5. copy former+latter -> out channels [0,512)
__global__ void copy_kernel(const float4* __restrict__ x4, float4* __restrict__ out4) {
    size_t i = (size_t)blockIdx.x * 256 + threadIdx.x;
    if (i >= (size_t)NB * NC * (HW / 4)) return;
    size_t p4 = i & 1023;
    size_t c  = (i >> 10) & 511;
    size_t b  = i >> 19;
    out4[(b * 768 + c) * 1024 + p4] = x4[i];
}

// --- 6. shift writeback with inline decode:
//     out[b, 512+c, p] = flag[p] ? lf[b, c, argmax_q(packed)] : 0
//     (fully overwrites the lfc/ffc scratch region — must run after argmax)
__global__ void shift_kernel(const float* __restrict__ x, const int* __restrict__ flag,
                             const unsigned long long* __restrict__ packed,
                             float* __restrict__ out) {
    int cc = blockIdx.x, b = blockIdx.y;
    const float* lfrow = x + ((size_t)b * NC + C2 + cc) * HW;
    float*       orow  = out + ((size_t)b * 768 + 512 + cc) * HW;
    const unsigned long long* pk = packed + (size_t)b * HW;
    for (int p = threadIdx.x; p < HW; p += 256) {
        float v = 0.f;
        if (flag[p] == 1) {
            unsigned low = (unsigned)(pk[p] & 0xFFFFFFFFull);
            int q = (int)((0xFFFFFFFFu - low) & (HW - 1));
            v = lfrow[q];
        }
        orow[p] = v;
    }
}

extern "C" void kernel_launch(void* const* d_in, const int* in_sizes, int n_in,
                              void* d_out, int out_size, void* d_ws, size_t ws_size,
                              hipStream_t stream) {
    const float* x    = (const float*)d_in[0];
    const int*   flag = (const int*)d_in[1];
    float*       out  = (float*)d_out;
    char*        ws   = (char*)d_ws;

    unsigned long long* packed = (unsigned long long*)(ws + WS_PACKED);
    int*   q0   = (int*)(ws + WS_Q0);
    int*   p1   = (int*)(ws + WS_P1);
    int*   cnt  = (int*)(ws + WS_CNT);
    float* invc = (float*)(ws + WS_INVC);

    hipMemsetAsync(packed, 0, (size_t)NB * HW * sizeof(unsigned long long), stream);

    compact_kernel<<<1, 256, 0, stream>>>(flag, q0, p1, cnt);
    pack_kernel<<<dim3(HW / 256, NC, NB), 256, 0, stream>>>(x, q0, p1, cnt, out);
    invc_kernel<<<dim3(HW / 256, NB), 256, 0, stream>>>(out, cnt, invc);
    copy_kernel<<<(NB * NC * (HW / 4) + 255) / 256, 256, 0, stream>>>((const float4*)x, (float4*)out);
    argmax_kernel<<<dim3(NB * NCHK * 32), 256, 0, stream>>>(out, invc, q0, p1, cnt, packed);
    shift_kernel<<<dim3(C2, NB), 256, 0, stream>>>(x, flag, packed, out);
}

// Round 11
// 264.091 us; speedup vs baseline: 1.0913x; 1.0380x over previous
//
#include <hip/hip_runtime.h>
#include <stdint.h>
#include <math.h>

#define HW   4096
#define NB   8
#define NC   512
#define C2   256
#define PT   32     // p-tile per block in argmax kernel
#define QC   256    // q-chunk per block (4 k per lane via one float4)
#define NCHK 16     // max chunks; chunk*QC >= n0 exits

// ---------- ws layout (bytes) ----------
#define WS_PACKED 0         // u64 packed[8*4096]            = 262144
#define WS_Q0     393216    // i32 q0list[4096]              = 16384
#define WS_P1     409600    // i32 p1list[4096]              = 16384
#define WS_CNT    425984    // i32 cnt[2]
#define WS_INVC   558080    // f32 invc[8*4096]              = 131072

__device__ __forceinline__ unsigned long long mkkey(float v, unsigned q) {
    unsigned u = __float_as_uint(v);
    u = (u & 0x80000000u) ? ~u : (u | 0x80000000u);   // monotone float -> u32
    return ((unsigned long long)u << 32) | (unsigned long long)(0xFFFFFFFFu - q);
}

// Packed scratch lives in d_out's shift region (channels [512,768) of batch b)
// = 1M floats per batch: lfc (C2 x ns) then ffc (C2 x ms). Written by
// pack_kernel, read by invc/argmax, then fully overwritten by shift_kernel.
__device__ __forceinline__ float* lfc_region(float* out, int b) {
    return out + ((size_t)b * 768 + 512) * HW;
}

// --- 1. deterministic sorted compaction of flag into p1 (flag==1) / q0 (flag==0)
__global__ void compact_kernel(const int* __restrict__ flag, int* __restrict__ q0,
                               int* __restrict__ p1, int* __restrict__ cnt) {
    __shared__ int c1s[256];
    int t = threadIdx.x;
    int f[16]; int n1 = 0;
    #pragma unroll
    for (int j = 0; j < 16; ++j) { f[j] = flag[t*16 + j]; n1 += (f[j] == 1); }
    c1s[t] = n1;
    __syncthreads();
    if (t == 0) {
        int run = 0;
        for (int i = 0; i < 256; ++i) { int v = c1s[i]; c1s[i] = run; run += v; }
        cnt[0] = run;          // n1
        cnt[1] = HW - run;     // n0
    }
    __syncthreads();
    int b1 = c1s[t];
    int b0 = t*16 - c1s[t];
    for (int j = 0; j < 16; ++j) {
        int i = t*16 + j;
        if (f[j] == 1) p1[b1++] = i; else q0[b0++] = i;
    }
}

// --- 2. fused copy + pack. Block (b, cy) reads row x[b][cy] once:
//     - coalesced copy: out[b][cy][i] = x[b][cy][i]
//     - cy <  256 (former): ffc[cy][m] = xrow[p1[m]]
//     - cy >= 256 (latter): lfc[cy-256][k] = xrow[q0[k]]
__global__ void pack_kernel(const float* __restrict__ x,
                            const int* __restrict__ q0, const int* __restrict__ p1,
                            const int* __restrict__ cnt, float* __restrict__ out) {
    int b = blockIdx.z, cy = blockIdx.y;
    int i = blockIdx.x * 256 + threadIdx.x;
    int n1 = cnt[0], n0 = cnt[1];
    int ns = (n0 + 3) & ~3, ms = (n1 + 3) & ~3;
    const float* xrow = x + ((size_t)b * NC + cy) * HW;
    out[((size_t)b * 768 + cy) * HW + i] = xrow[i];      // fused copy
    if (cy < C2) {
        if (i < n1) {
            float* ffc = lfc_region(out, b) + (size_t)C2 * ns;
            ffc[(size_t)cy * ms + i] = xrow[p1[i]];
        }
    } else {
        int c = cy - C2;
        if (i < n0) {
            float* lfc = lfc_region(out, b);
            lfc[(size_t)c * ns + i] = xrow[q0[i]];
        }
    }
}

// --- 2b. invc from packed lfc (coalesced; same c-ascending fp32 sum order
//     as the original norm kernel -> bit-identical values at q0 columns)
__global__ void invc_kernel(const float* __restrict__ out, const int* __restrict__ cnt,
                            float* __restrict__ invc) {
    int b = blockIdx.y;
    int n0 = cnt[1];
    int ns = (n0 + 3) & ~3;
    int k = blockIdx.x * 256 + threadIdx.x;
    if (k >= n0) return;
    const float* lfc = lfc_region((float*)out, b) + k;
    float s = 0.f;
    #pragma unroll 8
    for (int c = 0; c < C2; ++c) {
        float v = lfc[(size_t)c * ns];
        s = fmaf(v, v, s);
    }
    invc[b * HW + k] = 1.0f / fmaxf(sqrtf(s), 1e-8f);
}

// --- 3. cos + argmax over unmasked q, merged via packed atomicMax
//     R9 structure (best measured): QC=256, acc[8][4], one coalesced float4
//     per c from lfc; 1D grid XCD-swizzled (bid = b + 8*s -> batch b's 4MB
//     lfc+ffc working set pinned to XCD b's L2; R9: FETCH 148->16.6 MB).
//     NEW: prefetch depth 2 (f0..f3 rotating, unroll-by-2) to cover the
//     ~200cy L2 latency under ~64cy/row FMA issue (R9's 27% VALU idle).
//     Overrun prefetch at rows 256/257 lands in ffc scratch (valid, unused).
//     NOTE: no min-waves clamp in launch_bounds — (256,4) forced VGPR=64
//     and spilled acc to scratch (13 GB HBM, 7x regression in R3).
__global__ void __launch_bounds__(256) argmax_kernel(
        float* __restrict__ out, const float* __restrict__ invc,
        const int* __restrict__ q0, const int* __restrict__ p1,
        const int* __restrict__ cnt, unsigned long long* __restrict__ packed) {
    int bid   = blockIdx.x;
    int b     = bid & 7;
    int s     = bid >> 3;
    int chunk = s >> 5;
    int tile  = s & 31;
    int n1 = cnt[0], n0 = cnt[1];
    if (tile * PT >= n1) return;
    if (chunk * QC >= n0) return;
    int ns = (n0 + 3) & ~3, ms = (n1 + 3) & ~3;

    __shared__ float sff[128][PT];   // ff half-tile: [c][p] 16 KB

    int t = threadIdx.x;
    int tp = t >> 6;   // wave id -> 8-p sub-tile
    int tq = t & 63;   // lane    -> k group of 4

    const float* lfc = lfc_region(out, b);
    const float* ffc = lfc + (size_t)C2 * ns;
    int kbase = chunk * QC + tq * 4;   // 16B aligned

    const float* r = lfc + kbase;      // points at row c of f0
    float4 f0 = *(const float4*)(r);
    float4 f1 = *(const float4*)(r + ns);

    float acc[8][4];
    #pragma unroll
    for (int pi = 0; pi < 8; ++pi)
        #pragma unroll
        for (int j = 0; j < 4; ++j) acc[pi][j] = 0.f;

    bool fulltile = (tile * PT + PT <= n1);

    for (int h = 0; h < 2; ++h) {
        __syncthreads();   // h=1: all waves done reading sff half 0
        if (fulltile) {
            #pragma unroll
            for (int k = 0; k < 4; ++k) {       // 1024 float4 / 256 threads
                int i4 = t + (k << 8);
                int c = i4 >> 3, jg = i4 & 7;
                ((float4*)sff)[i4] =
                    *(const float4*)&ffc[(size_t)(h * 128 + c) * ms + tile * PT + jg * 4];
            }
        } else {
            #pragma unroll
            for (int k = 0; k < 4; ++k) {
                int i4 = t + (k << 8);
                int c = i4 >> 3, jg = i4 & 7;
                const float* src = &ffc[(size_t)(h * 128 + c) * ms];
                int m0 = tile * PT + jg * 4;
                float4 v;
                v.x = (m0 + 0 < n1) ? src[m0 + 0] : 0.f;
                v.y = (m0 + 1 < n1) ? src[m0 + 1] : 0.f;
                v.z = (m0 + 2 < n1) ? src[m0 + 2] : 0.f;
                v.w = (m0 + 3 < n1) ? src[m0 + 3] : 0.f;
                ((float4*)sff)[i4] = v;
            }
        }
        __syncthreads();

        #pragma unroll 2
        for (int cc = 0; cc < 128; cc += 2) {
            // depth-2 prefetch: rows c+2, c+3 in flight while computing c, c+1
            float4 f2 = *(const float4*)(r + 2 * (size_t)ns);
            {
                const float4* arow = (const float4*)&sff[cc][tp * 8];
                float4 a0 = arow[0], a1 = arow[1];
                float av[8] = {a0.x, a0.y, a0.z, a0.w, a1.x, a1.y, a1.z, a1.w};
                #pragma unroll
                for (int pi = 0; pi < 8; ++pi) {
                    acc[pi][0] = fmaf(av[pi], f0.x, acc[pi][0]);
                    acc[pi][1] = fmaf(av[pi], f0.y, acc[pi][1]);
                    acc[pi][2] = fmaf(av[pi], f0.z, acc[pi][2]);
                    acc[pi][3] = fmaf(av[pi], f0.w, acc[pi][3]);
                }
            }
            float4 f3 = *(const float4*)(r + 3 * (size_t)ns);
            {
                const float4* arow = (const float4*)&sff[cc + 1][tp * 8];
                float4 a0 = arow[0], a1 = arow[1];
                float av[8] = {a0.x, a0.y, a0.z, a0.w, a1.x, a1.y, a1.z, a1.w};
                #pragma unroll
                for (int pi = 0; pi < 8; ++pi) {
                    acc[pi][0] = fmaf(av[pi], f1.x, acc[pi][0]);
                    acc[pi][1] = fmaf(av[pi], f1.y, acc[pi][1]);
                    acc[pi][2] = fmaf(av[pi], f1.z, acc[pi][2]);
                    acc[pi][3] = fmaf(av[pi], f1.w, acc[pi][3]);
                }
            }
            f0 = f2; f1 = f3;
            r += 2 * (size_t)ns;
        }
    }

    float best[8];
    int   bq[8];
    #pragma unroll
    for (int pi = 0; pi < 8; ++pi) { best[pi] = -INFINITY; bq[pi] = 0x7FFFFFFF; }

    #pragma unroll
    for (int j = 0; j < 4; ++j) {
        int k = kbase + j;
        if (k >= n0) continue;
        float sc = invc[b * HW + k];
        int   q  = q0[k];
        #pragma unroll
        for (int pi = 0; pi < 8; ++pi) {
            float cv = acc[pi][j] * sc;
            if (cv > best[pi] || (cv == best[pi] && q < bq[pi])) {
                best[pi] = cv; bq[pi] = q;
            }
        }
    }

    // wave reduce (all 64 lanes share the same 8 p's)
    #pragma unroll
    for (int m = 1; m < 64; m <<= 1) {
        #pragma unroll
        for (int pi = 0; pi < 8; ++pi) {
            float ov = __shfl_xor(best[pi], m);
            int   oq = __shfl_xor(bq[pi], m);
            if (ov > best[pi] || (ov == best[pi] && oq < bq[pi])) {
                best[pi] = ov; bq[pi] = oq;
            }
        }
    }
    if (tq == 0) {
        #pragma unroll
        for (int pi = 0; pi < 8; ++pi) {
            int pidx = tile * PT + tp * 8 + pi;
            int p = (pidx < n1) ? p1[pidx] : -1;
            if (p >= 0)
                atomicMax(&packed[(size_t)b * HW + p], mkkey(best[pi], (unsigned)bq[pi]));
        }
    }
}

// --- 4. shift writeback with inline decode:
//     out[b, 512+c, p] = flag[p] ? lf[b, c, argmax_q(packed)] : 0
//     (fully overwrites the lfc/ffc scratch region — must run after argmax)
__global__ void shift_kernel(const float* __restrict__ x, const int* __restrict__ flag,
                             const unsigned long long* __restrict__ packed,
                             float* __restrict__ out) {
    int cc = blockIdx.x, b = blockIdx.y;
    const float* lfrow = x + ((size_t)b * NC + C2 + cc) * HW;
    float*       orow  = out + ((size_t)b * 768 + 512 + cc) * HW;
    const unsigned long long* pk = packed + (size_t)b * HW;
    for (int p = threadIdx.x; p < HW; p += 256) {
        float v = 0.f;
        if (flag[p] == 1) {
            unsigned low = (unsigned)(pk[p] & 0xFFFFFFFFull);
            int q = (int)((0xFFFFFFFFu - low) & (HW - 1));
            v = lfrow[q];
        }
        orow[p] = v;
    }
}

extern "C" void kernel_launch(void* const* d_in, const int* in_sizes, int n_in,
                              void* d_out, int out_size, void* d_ws, size_t ws_size,
                              hipStream_t stream) {
    const float* x    = (const float*)d_in[0];
    const int*   flag = (const int*)d_in[1];
    float*       out  = (float*)d_out;
    char*        ws   = (char*)d_ws;

    unsigned long long* packed = (unsigned long long*)(ws + WS_PACKED);
    int*   q0   = (int*)(ws + WS_Q0);
    int*   p1   = (int*)(ws + WS_P1);
    int*   cnt  = (int*)(ws + WS_CNT);
    float* invc = (float*)(ws + WS_INVC);

    hipMemsetAsync(packed, 0, (size_t)NB * HW * sizeof(unsigned long long), stream);

    compact_kernel<<<1, 256, 0, stream>>>(flag, q0, p1, cnt);
    pack_kernel<<<dim3(HW / 256, NC, NB), 256, 0, stream>>>(x, q0, p1, cnt, out);
    invc_kernel<<<dim3(HW / 256, NB), 256, 0, stream>>>(out, cnt, invc);
    argmax_kernel<<<dim3(NB * NCHK * 32), 256, 0, stream>>>(out, invc, q0, p1, cnt, packed);
    shift_kernel<<<dim3(C2, NB), 256, 0, stream>>>(x, flag, packed, out);
}